// Round 1
// baseline (846.214 us; speedup 1.0000x reference)
//
#include <hip/hip_runtime.h>
#include <math.h>

constexpr int N_NODES = 50000;
constexpr int N_EDGES = 400000;
constexpr int IN_F = 512;
constexpr int HEADS = 8;
constexpr int OUT_F = 64;
constexpr int HF = 512;       // HEADS * OUT_F
constexpr float NEG = 0.2f;

// ---------------------------------------------------------------------------
// K1: fold attention vectors into the projection matrices.
// w_l[k][h] = sum_f W_src[k][h*64+f] * attn_l[h][f]   (512x8)
// c_l[h]    = sum_f b_src[h*64+f]   * attn_l[h][f]
// (same for w_r/c_r with W_dst/b_dst/attn_r)
// ---------------------------------------------------------------------------
__global__ void k1_fold(const float* __restrict__ W_src, const float* __restrict__ b_src,
                        const float* __restrict__ W_dst, const float* __restrict__ b_dst,
                        const float* __restrict__ attn_l, const float* __restrict__ attn_r,
                        float* __restrict__ w_l, float* __restrict__ w_r,
                        float* __restrict__ c_l, float* __restrict__ c_r) {
    int gid = blockIdx.x * 256 + threadIdx.x;
    if (gid < 4096) {
        int k = gid >> 3, h = gid & 7;
        float s = 0.f;
        #pragma unroll 8
        for (int f = 0; f < OUT_F; ++f) s += W_src[k * HF + h * OUT_F + f] * attn_l[h * OUT_F + f];
        w_l[k * 8 + h] = s;
    } else if (gid < 8192) {
        int g = gid - 4096;
        int k = g >> 3, h = g & 7;
        float s = 0.f;
        #pragma unroll 8
        for (int f = 0; f < OUT_F; ++f) s += W_dst[k * HF + h * OUT_F + f] * attn_r[h * OUT_F + f];
        w_r[k * 8 + h] = s;
    } else if (gid < 8192 + 16) {
        int g = gid - 8192;
        int h = g & 7;
        float s = 0.f;
        if (g < 8) {
            for (int f = 0; f < OUT_F; ++f) s += b_src[h * OUT_F + f] * attn_l[h * OUT_F + f];
            c_l[h] = s;
        } else {
            for (int f = 0; f < OUT_F; ++f) s += b_dst[h * OUT_F + f] * attn_r[h * OUT_F + f];
            c_r[h] = s;
        }
    }
}

// ---------------------------------------------------------------------------
// K2: el[n][h] = feat[n,:] @ w_l[:,h] + c_l[h]; er likewise.
// Also zero-inits denom and deg. 16 threads per node (8 el + 8 er).
// ---------------------------------------------------------------------------
__global__ __launch_bounds__(256) void k2_el_er(
        const float* __restrict__ feat,
        const float* __restrict__ w_l, const float* __restrict__ w_r,
        const float* __restrict__ c_l, const float* __restrict__ c_r,
        float* __restrict__ el, float* __restrict__ er,
        float* __restrict__ denom, int* __restrict__ deg) {
    __shared__ float swl[4096];
    __shared__ float swr[4096];
    int t = threadIdx.x;
    for (int i = t; i < 4096; i += 256) { swl[i] = w_l[i]; swr[i] = w_r[i]; }
    __syncthreads();

    int node = blockIdx.x * 16 + (t >> 4);
    if (node >= N_NODES) return;
    int sub = t & 15, h = sub & 7, side = sub >> 3;

    if (sub < 8) denom[node * 8 + sub] = 0.f;
    if (sub == 8) deg[node] = 0;

    const float* w = side ? swr : swl;
    float acc = side ? c_r[h] : c_l[h];
    const float* frow = feat + (size_t)node * IN_F;
    for (int k = 0; k < IN_F; k += 4) {
        float4 f = *(const float4*)(frow + k);
        acc = fmaf(f.x, w[(k + 0) * 8 + h], acc);
        acc = fmaf(f.y, w[(k + 1) * 8 + h], acc);
        acc = fmaf(f.z, w[(k + 2) * 8 + h], acc);
        acc = fmaf(f.w, w[(k + 3) * 8 + h], acc);
    }
    if (side) er[node * 8 + h] = acc; else el[node * 8 + h] = acc;
}

// ---------------------------------------------------------------------------
// K3: feat_v = feat @ W_val + b_val   (50000 x 512 x 512, fp32 tiled)
// BM=128, BN=64, BK=16; 256 threads; 8x4 microtile per thread.
// ---------------------------------------------------------------------------
constexpr int BM = 128, BN = 64, BK = 16;

__global__ __launch_bounds__(256) void k3_gemm(
        const float* __restrict__ A,     // feat  [M][512]
        const float* __restrict__ B,     // W_val [512][512]
        const float* __restrict__ bias,  // b_val [512]
        float* __restrict__ C) {         // feat_v [M][512]
    __shared__ float As[BK][BM];
    __shared__ float Bs[BK][BN];
    int t = threadIdx.x;
    int bn = blockIdx.x & 7;
    int bm = blockIdx.x >> 3;
    int rowBase = bm * BM;
    int colBase = bn * BN;
    int tx = t & 15, ty = t >> 4;

    float acc[8][4] = {};

    int rA = t >> 2;            // 0..63 (and +64 for second half)
    int kA = (t & 3) * 4;       // 0,4,8,12
    int kB = t >> 4;            // 0..15
    int nB = (t & 15) * 4;      // 0..60

    for (int k0 = 0; k0 < IN_F; k0 += BK) {
        #pragma unroll
        for (int half = 0; half < 2; ++half) {
            int r = rA + half * 64;
            int grow = rowBase + r;
            float4 v = make_float4(0.f, 0.f, 0.f, 0.f);
            if (grow < N_NODES) v = *(const float4*)(A + (size_t)grow * IN_F + k0 + kA);
            As[kA + 0][r] = v.x; As[kA + 1][r] = v.y;
            As[kA + 2][r] = v.z; As[kA + 3][r] = v.w;
        }
        {
            float4 v = *(const float4*)(B + (size_t)(k0 + kB) * HF + colBase + nB);
            *(float4*)&Bs[kB][nB] = v;
        }
        __syncthreads();
        #pragma unroll
        for (int k = 0; k < BK; ++k) {
            float a[8], b[4];
            #pragma unroll
            for (int i = 0; i < 8; ++i) a[i] = As[k][ty * 8 + i];
            #pragma unroll
            for (int j = 0; j < 4; ++j) b[j] = Bs[k][tx * 4 + j];
            #pragma unroll
            for (int i = 0; i < 8; ++i)
                #pragma unroll
                for (int j = 0; j < 4; ++j)
                    acc[i][j] = fmaf(a[i], b[j], acc[i][j]);
        }
        __syncthreads();
    }

    int col = colBase + tx * 4;
    float4 bv = *(const float4*)(bias + col);
    #pragma unroll
    for (int i = 0; i < 8; ++i) {
        int grow = rowBase + ty * 8 + i;
        if (grow >= N_NODES) continue;
        float4 v;
        v.x = acc[i][0] + bv.x;
        v.y = acc[i][1] + bv.y;
        v.z = acc[i][2] + bv.z;
        v.w = acc[i][3] + bv.w;
        *(float4*)(C + (size_t)grow * HF + col) = v;
    }
}

// ---------------------------------------------------------------------------
// K4: histogram of dst -> deg
// ---------------------------------------------------------------------------
__global__ void k4_hist(const int* __restrict__ dst, int* __restrict__ deg) {
    int e = blockIdx.x * 256 + threadIdx.x;
    if (e < N_EDGES) atomicAdd(&deg[dst[e]], 1);
}

// ---------------------------------------------------------------------------
// K5: exclusive prefix sum over deg -> offsets (and cursor copy).
// One block of 1024 threads; wave shuffles + small LDS combine.
// ---------------------------------------------------------------------------
__global__ __launch_bounds__(1024) void k5_scan(const int* __restrict__ deg,
                                                int* __restrict__ offsets,
                                                int* __restrict__ cursor) {
    __shared__ int wsum[16];
    __shared__ int carry_s;
    int t = threadIdx.x;
    int lane = t & 63, wid = t >> 6;
    if (t == 0) carry_s = 0;
    __syncthreads();
    for (int base = 0; base < N_NODES; base += 1024) {
        int i = base + t;
        int v = (i < N_NODES) ? deg[i] : 0;
        int x = v;
        #pragma unroll
        for (int off = 1; off < 64; off <<= 1) {
            int y = __shfl_up(x, (unsigned)off, 64);
            if (lane >= off) x += y;
        }
        if (lane == 63) wsum[wid] = x;
        __syncthreads();
        if (wid == 0) {
            int s = (lane < 16) ? wsum[lane] : 0;
            #pragma unroll
            for (int off = 1; off < 16; off <<= 1) {
                int y = __shfl_up(s, (unsigned)off, 64);
                if (lane >= off) s += y;
            }
            if (lane < 16) wsum[lane] = s;
        }
        __syncthreads();
        int waveoff = (wid == 0) ? 0 : wsum[wid - 1];
        int c0 = carry_s;
        int excl = c0 + waveoff + x - v;
        if (i < N_NODES) { offsets[i] = excl; cursor[i] = excl; }
        __syncthreads();
        if (t == 0) carry_s = c0 + wsum[15];
        __syncthreads();
    }
}

// ---------------------------------------------------------------------------
// K6: scatter edge ids into CSR order by dst.
// ---------------------------------------------------------------------------
__global__ void k6_scatter(const int* __restrict__ dst, int* __restrict__ cursor,
                           int* __restrict__ eidx) {
    int e = blockIdx.x * 256 + threadIdx.x;
    if (e < N_EDGES) {
        int pos = atomicAdd(&cursor[dst[e]], 1);
        eidx[pos] = e;
    }
}

// ---------------------------------------------------------------------------
// K7: per-edge logits -> exp, accumulate denom per (dst, h).
// No max-subtraction: logits bounded (|e| ~< 6), exp safe in fp32,
// mathematically identical to the max-shifted softmax.
// ---------------------------------------------------------------------------
__global__ void k7_edge(const int* __restrict__ src, const int* __restrict__ dst,
                        const float* __restrict__ el, const float* __restrict__ er,
                        float* __restrict__ exp_e, float* __restrict__ denom) {
    int idx = blockIdx.x * 256 + threadIdx.x;
    if (idx >= N_EDGES * 8) return;
    int e = idx >> 3, h = idx & 7;
    float v = el[src[e] * 8 + h] + er[dst[e] * 8 + h];
    v = (v >= 0.f) ? v : NEG * v;
    float ex = expf(v);
    exp_e[idx] = ex;
    atomicAdd(&denom[dst[e] * 8 + h], ex);
}

// ---------------------------------------------------------------------------
// K8: aggregation. One block per dst node; thread t owns features t, t+256.
// ---------------------------------------------------------------------------
__global__ __launch_bounds__(256) void k8_agg(
        const int* __restrict__ src, const int* __restrict__ eidx,
        const int* __restrict__ offsets, const int* __restrict__ deg,
        const float* __restrict__ exp_e, const float* __restrict__ denom,
        const float* __restrict__ feat_v, float* __restrict__ out) {
    int n = blockIdx.x;
    int t = threadIdx.x;
    int start = offsets[n];
    int cnt = deg[n];
    int h0 = t >> 6;        // 0..3
    int h1 = h0 + 4;        // 4..7
    float d0 = 1.f / fmaxf(denom[n * 8 + h0], 1e-16f);
    float d1 = 1.f / fmaxf(denom[n * 8 + h1], 1e-16f);
    float acc0 = 0.f, acc1 = 0.f;
    for (int i = 0; i < cnt; ++i) {
        int e = eidx[start + i];
        int s = src[e];
        float w0 = exp_e[e * 8 + h0] * d0;
        float w1 = exp_e[e * 8 + h1] * d1;
        const float* fv = feat_v + (size_t)s * HF;
        acc0 = fmaf(w0, fv[t], acc0);
        acc1 = fmaf(w1, fv[t + 256], acc1);
    }
    out[(size_t)n * HF + t] = acc0;
    out[(size_t)n * HF + t + 256] = acc1;
}

// ---------------------------------------------------------------------------
extern "C" void kernel_launch(void* const* d_in, const int* in_sizes, int n_in,
                              void* d_out, int out_size, void* d_ws, size_t ws_size,
                              hipStream_t stream) {
    const float* feat   = (const float*)d_in[0];
    const int*   src    = (const int*)d_in[1];
    const int*   dst    = (const int*)d_in[2];
    const float* W_src  = (const float*)d_in[3];
    const float* b_src  = (const float*)d_in[4];
    const float* W_dst  = (const float*)d_in[5];
    const float* b_dst  = (const float*)d_in[6];
    const float* W_val  = (const float*)d_in[7];
    const float* b_val  = (const float*)d_in[8];
    const float* attn_l = (const float*)d_in[9];
    const float* attn_r = (const float*)d_in[10];
    float* out = (float*)d_out;

    char* ws = (char*)d_ws;
    size_t off = 0;
    auto alloc = [&](size_t bytes) -> void* {
        void* p = ws + off;
        off += (bytes + 255) & ~(size_t)255;
        return p;
    };

    float* w_l    = (float*)alloc(4096 * 4);
    float* w_r    = (float*)alloc(4096 * 4);
    float* c_l    = (float*)alloc(8 * 4);
    float* c_r    = (float*)alloc(8 * 4);
    float* el     = (float*)alloc((size_t)N_NODES * 8 * 4);
    float* er     = (float*)alloc((size_t)N_NODES * 8 * 4);
    float* denom  = (float*)alloc((size_t)N_NODES * 8 * 4);
    float* exp_e  = (float*)alloc((size_t)N_EDGES * 8 * 4);
    float* feat_v = (float*)alloc((size_t)N_NODES * HF * 4);
    int*   deg    = (int*)alloc((size_t)N_NODES * 4);
    int*   offs   = (int*)alloc((size_t)N_NODES * 4);
    int*   cursor = (int*)alloc((size_t)N_NODES * 4);
    int*   eidx   = (int*)alloc((size_t)N_EDGES * 4);
    (void)ws_size; (void)in_sizes; (void)n_in; (void)out_size;

    k1_fold<<<33, 256, 0, stream>>>(W_src, b_src, W_dst, b_dst, attn_l, attn_r,
                                    w_l, w_r, c_l, c_r);
    k2_el_er<<<(N_NODES + 15) / 16, 256, 0, stream>>>(feat, w_l, w_r, c_l, c_r,
                                                      el, er, denom, deg);
    k3_gemm<<<((N_NODES + BM - 1) / BM) * 8, 256, 0, stream>>>(feat, W_val, b_val, feat_v);
    k4_hist<<<(N_EDGES + 255) / 256, 256, 0, stream>>>(dst, deg);
    k5_scan<<<1, 1024, 0, stream>>>(deg, offs, cursor);
    k6_scatter<<<(N_EDGES + 255) / 256, 256, 0, stream>>>(dst, cursor, eidx);
    k7_edge<<<(N_EDGES * 8 + 255) / 256, 256, 0, stream>>>(src, dst, el, er, exp_e, denom);
    k8_agg<<<N_NODES, 256, 0, stream>>>(src, eidx, offs, deg, exp_e, denom, feat_v, out);
}

// Round 2
// 565.597 us; speedup vs baseline: 1.4961x; 1.4961x over previous
//
#include <hip/hip_runtime.h>
#include <math.h>

constexpr int N_NODES = 50000;
constexpr int N_PAD   = 50048;    // 391 * 128, padded rows for tile overrun
constexpr int N_EDGES = 400000;
constexpr int IN_F = 512;
constexpr int HEADS = 8;
constexpr int OUT_F = 64;
constexpr int HF = 512;           // HEADS * OUT_F
constexpr float NEG = 0.2f;

typedef __bf16 bf16x8 __attribute__((ext_vector_type(8)));
typedef float  f32x4  __attribute__((ext_vector_type(4)));

__device__ __forceinline__ unsigned short f2bf(float f) {
    unsigned u = __float_as_uint(f);
    u += 0x7fffu + ((u >> 16) & 1u);   // round-to-nearest-even (inputs finite)
    return (unsigned short)(u >> 16);
}
__device__ __forceinline__ unsigned packbf2(float lo, float hi) {
    return (unsigned)f2bf(lo) | ((unsigned)f2bf(hi) << 16);
}

// ---------------------------------------------------------------------------
// K0: feat fp32 -> bf16 (padded rows left as-is; poison there is finite/tiny)
// ---------------------------------------------------------------------------
__global__ __launch_bounds__(256) void k0_convert(const float* __restrict__ in,
                                                  unsigned short* __restrict__ out) {
    int idx = blockIdx.x * 256 + threadIdx.x;     // 3,200,000 threads, 8 floats each
    size_t base = (size_t)idx * 8;
    float4 a = *(const float4*)(in + base);
    float4 b = *(const float4*)(in + base + 4);
    uint4 v;
    v.x = packbf2(a.x, a.y);
    v.y = packbf2(a.z, a.w);
    v.z = packbf2(b.x, b.y);
    v.w = packbf2(b.z, b.w);
    *(uint4*)(out + base) = v;
}

// ---------------------------------------------------------------------------
// K0b: W_val fp32 [K][N] -> Wt bf16 [N][K] (transpose + convert), 32x32 tiles
// ---------------------------------------------------------------------------
__global__ __launch_bounds__(256) void k0b_wt(const float* __restrict__ W,
                                              unsigned short* __restrict__ Wt) {
    __shared__ float tile[32][33];
    int bi = blockIdx.x >> 4;   // k-tile
    int bj = blockIdx.x & 15;   // n-tile
    for (int i = threadIdx.x; i < 1024; i += 256) {
        int r = i >> 5, c = i & 31;
        tile[r][c] = W[(size_t)(bi * 32 + r) * HF + bj * 32 + c];
    }
    __syncthreads();
    for (int i = threadIdx.x; i < 1024; i += 256) {
        int r = i >> 5, c = i & 31;   // r = n-local, c = k-local
        Wt[(size_t)(bj * 32 + r) * IN_F + bi * 32 + c] = f2bf(tile[c][r]);
    }
}

// ---------------------------------------------------------------------------
// K1: fold attention vectors into projection matrices (512x8 each + consts)
// ---------------------------------------------------------------------------
__global__ void k1_fold(const float* __restrict__ W_src, const float* __restrict__ b_src,
                        const float* __restrict__ W_dst, const float* __restrict__ b_dst,
                        const float* __restrict__ attn_l, const float* __restrict__ attn_r,
                        float* __restrict__ w_l, float* __restrict__ w_r,
                        float* __restrict__ c_l, float* __restrict__ c_r) {
    int gid = blockIdx.x * 256 + threadIdx.x;
    if (gid < 4096) {
        int k = gid >> 3, h = gid & 7;
        float s = 0.f;
        #pragma unroll 8
        for (int f = 0; f < OUT_F; ++f) s += W_src[k * HF + h * OUT_F + f] * attn_l[h * OUT_F + f];
        w_l[k * 8 + h] = s;
    } else if (gid < 8192) {
        int g = gid - 4096;
        int k = g >> 3, h = g & 7;
        float s = 0.f;
        #pragma unroll 8
        for (int f = 0; f < OUT_F; ++f) s += W_dst[k * HF + h * OUT_F + f] * attn_r[h * OUT_F + f];
        w_r[k * 8 + h] = s;
    } else if (gid < 8192 + 16) {
        int g = gid - 8192;
        int h = g & 7;
        float s = 0.f;
        if (g < 8) {
            for (int f = 0; f < OUT_F; ++f) s += b_src[h * OUT_F + f] * attn_l[h * OUT_F + f];
            c_l[h] = s;
        } else {
            for (int f = 0; f < OUT_F; ++f) s += b_dst[h * OUT_F + f] * attn_r[h * OUT_F + f];
            c_r[h] = s;
        }
    }
}

// ---------------------------------------------------------------------------
// K2: el/er = feat @ w_l/w_r + c; also zero-inits denom and deg.
// ---------------------------------------------------------------------------
__global__ __launch_bounds__(256) void k2_el_er(
        const float* __restrict__ feat,
        const float* __restrict__ w_l, const float* __restrict__ w_r,
        const float* __restrict__ c_l, const float* __restrict__ c_r,
        float* __restrict__ el, float* __restrict__ er,
        float* __restrict__ denom, int* __restrict__ deg) {
    __shared__ float swl[4096];
    __shared__ float swr[4096];
    int t = threadIdx.x;
    for (int i = t; i < 4096; i += 256) { swl[i] = w_l[i]; swr[i] = w_r[i]; }
    __syncthreads();

    int node = blockIdx.x * 16 + (t >> 4);
    if (node >= N_NODES) return;
    int sub = t & 15, h = sub & 7, side = sub >> 3;

    if (sub < 8) denom[node * 8 + sub] = 0.f;
    if (sub == 8) deg[node] = 0;

    const float* w = side ? swr : swl;
    float acc = side ? c_r[h] : c_l[h];
    const float* frow = feat + (size_t)node * IN_F;
    for (int k = 0; k < IN_F; k += 4) {
        float4 f = *(const float4*)(frow + k);
        acc = fmaf(f.x, w[(k + 0) * 8 + h], acc);
        acc = fmaf(f.y, w[(k + 1) * 8 + h], acc);
        acc = fmaf(f.z, w[(k + 2) * 8 + h], acc);
        acc = fmaf(f.w, w[(k + 3) * 8 + h], acc);
    }
    if (side) er[node * 8 + h] = acc; else el[node * 8 + h] = acc;
}

// ---------------------------------------------------------------------------
// K3: feat_v = feat @ W_val + b_val via bf16 MFMA (m97 structure).
// 128x128 tile, BK=64, global_load_lds(16B) staging with XOR chunk swizzle
// (physical chunk p at row r holds logical chunk p^(r&7)) so the b128
// fragment reads are 2-way (free) instead of 16-way conflicted.
// 4 waves in 2x2; each wave: 64x64 via 4x4 grid of 16x16x32 MFMA.
// Output stored as bf16 [N_PAD][512].
// ---------------------------------------------------------------------------
__global__ __launch_bounds__(256) void k3_mfma(
        const unsigned short* __restrict__ Abf,   // feat bf16 [N_PAD][512]
        const unsigned short* __restrict__ Bbf,   // Wt bf16 [512][512] (n-major)
        const float* __restrict__ bias,
        unsigned short* __restrict__ C) {         // feat_v bf16 [N_PAD][512]
    __shared__ unsigned short As[128 * 64];
    __shared__ unsigned short Bs[128 * 64];
    int tid = threadIdx.x;
    int w = tid >> 6, lane = tid & 63;
    int bm = blockIdx.x >> 2, bn = blockIdx.x & 3;
    int rowBase = bm * 128, colBase = bn * 128;
    int wm = w >> 1, wn = w & 1;
    int c15 = lane & 15, q = lane >> 4;

    f32x4 acc[4][4] = {};

    for (int k0 = 0; k0 < IN_F; k0 += 64) {
        // ---- stage A (16 KB) and B (16 KB): 4 rounds each per wave ----
        #pragma unroll
        for (int rnd = 0; rnd < 4; ++rnd) {
            int e = w * 256 + rnd * 64 + lane;     // chunk index 0..1023
            int r = e >> 3, p = e & 7;
            int lc = p ^ (r & 7);                  // logical k-chunk fetched here
            const unsigned short* gA = Abf + (size_t)(rowBase + r) * IN_F + k0 + lc * 8;
            unsigned short* lA = &As[(w * 256 + rnd * 64) * 8];
            __builtin_amdgcn_global_load_lds(
                (const __attribute__((address_space(1))) unsigned int*)gA,
                (__attribute__((address_space(3))) unsigned int*)lA, 16, 0, 0);
            const unsigned short* gB = Bbf + (size_t)(colBase + r) * IN_F + k0 + lc * 8;
            unsigned short* lB = &Bs[(w * 256 + rnd * 64) * 8];
            __builtin_amdgcn_global_load_lds(
                (const __attribute__((address_space(1))) unsigned int*)gB,
                (__attribute__((address_space(3))) unsigned int*)lB, 16, 0, 0);
        }
        __syncthreads();

        #pragma unroll
        for (int ks = 0; ks < 2; ++ks) {
            bf16x8 a[4], b[4];
            #pragma unroll
            for (int mi = 0; mi < 4; ++mi) {
                int row = wm * 64 + mi * 16 + c15;
                int pc = (ks * 4 + q) ^ (row & 7);
                a[mi] = *(const bf16x8*)&As[row * 64 + pc * 8];
            }
            #pragma unroll
            for (int nj = 0; nj < 4; ++nj) {
                int row = wn * 64 + nj * 16 + c15;
                int pc = (ks * 4 + q) ^ (row & 7);
                b[nj] = *(const bf16x8*)&Bs[row * 64 + pc * 8];
            }
            #pragma unroll
            for (int mi = 0; mi < 4; ++mi)
                #pragma unroll
                for (int nj = 0; nj < 4; ++nj)
                    acc[mi][nj] = __builtin_amdgcn_mfma_f32_16x16x32_bf16(
                        a[mi], b[nj], acc[mi][nj], 0, 0, 0);
        }
        __syncthreads();
    }

    // epilogue: C/D layout col=lane&15, row=q*4+reg  [m89-verified]
    #pragma unroll
    for (int nj = 0; nj < 4; ++nj) {
        int col = colBase + wn * 64 + nj * 16 + c15;
        float bv = bias[col];
        #pragma unroll
        for (int mi = 0; mi < 4; ++mi) {
            int row0 = rowBase + wm * 64 + mi * 16 + q * 4;
            #pragma unroll
            for (int rg = 0; rg < 4; ++rg) {
                C[(size_t)(row0 + rg) * HF + col] = f2bf(acc[mi][nj][rg] + bv);
            }
        }
    }
}

// ---------------------------------------------------------------------------
// K4: histogram of dst -> deg
// ---------------------------------------------------------------------------
__global__ void k4_hist(const int* __restrict__ dst, int* __restrict__ deg) {
    int e = blockIdx.x * 256 + threadIdx.x;
    if (e < N_EDGES) atomicAdd(&deg[dst[e]], 1);
}

// ---------------------------------------------------------------------------
// K5: exclusive prefix sum over deg (single block, wave shuffles)
// ---------------------------------------------------------------------------
__global__ __launch_bounds__(1024) void k5_scan(const int* __restrict__ deg,
                                                int* __restrict__ offsets,
                                                int* __restrict__ cursor) {
    __shared__ int wsum[16];
    __shared__ int carry_s;
    int t = threadIdx.x;
    int lane = t & 63, wid = t >> 6;
    if (t == 0) carry_s = 0;
    __syncthreads();
    for (int base = 0; base < N_NODES; base += 1024) {
        int i = base + t;
        int v = (i < N_NODES) ? deg[i] : 0;
        int x = v;
        #pragma unroll
        for (int off = 1; off < 64; off <<= 1) {
            int y = __shfl_up(x, (unsigned)off, 64);
            if (lane >= off) x += y;
        }
        if (lane == 63) wsum[wid] = x;
        __syncthreads();
        if (wid == 0) {
            int s = (lane < 16) ? wsum[lane] : 0;
            #pragma unroll
            for (int off = 1; off < 16; off <<= 1) {
                int y = __shfl_up(s, (unsigned)off, 64);
                if (lane >= off) s += y;
            }
            if (lane < 16) wsum[lane] = s;
        }
        __syncthreads();
        int waveoff = (wid == 0) ? 0 : wsum[wid - 1];
        int c0 = carry_s;
        int excl = c0 + waveoff + x - v;
        if (i < N_NODES) { offsets[i] = excl; cursor[i] = excl; }
        __syncthreads();
        if (t == 0) carry_s = c0 + wsum[15];
        __syncthreads();
    }
}

// ---------------------------------------------------------------------------
// K6: scatter edge ids into CSR order by dst
// ---------------------------------------------------------------------------
__global__ void k6_scatter(const int* __restrict__ dst, int* __restrict__ cursor,
                           int* __restrict__ eidx) {
    int e = blockIdx.x * 256 + threadIdx.x;
    if (e < N_EDGES) {
        int pos = atomicAdd(&cursor[dst[e]], 1);
        eidx[pos] = e;
    }
}

// ---------------------------------------------------------------------------
// K7: per-edge exp(leaky_relu(logit)), accumulate denom per (dst,h).
// No max-subtraction: |logit| bounded small, exp safe in fp32, identical math.
// ---------------------------------------------------------------------------
__global__ void k7_edge(const int* __restrict__ src, const int* __restrict__ dst,
                        const float* __restrict__ el, const float* __restrict__ er,
                        float* __restrict__ exp_e, float* __restrict__ denom) {
    int idx = blockIdx.x * 256 + threadIdx.x;
    if (idx >= N_EDGES * 8) return;
    int e = idx >> 3, h = idx & 7;
    float v = el[src[e] * 8 + h] + er[dst[e] * 8 + h];
    v = (v >= 0.f) ? v : NEG * v;
    float ex = expf(v);
    exp_e[idx] = ex;
    atomicAdd(&denom[dst[e] * 8 + h], ex);
}

// ---------------------------------------------------------------------------
// K8: aggregation over CSR. One block per dst node; thread t owns features
// 2t, 2t+1 (one uint = 2 bf16 per edge -> halved gather traffic).
// ---------------------------------------------------------------------------
__global__ __launch_bounds__(256) void k8_agg(
        const int* __restrict__ src, const int* __restrict__ eidx,
        const int* __restrict__ offsets, const int* __restrict__ deg,
        const float* __restrict__ exp_e, const float* __restrict__ denom,
        const unsigned int* __restrict__ feat_v,   // bf16x2 per uint, row=256 uints
        float* __restrict__ out) {
    int n = blockIdx.x;
    int t = threadIdx.x;
    int start = offsets[n];
    int cnt = deg[n];
    int h = t >> 5;                    // feature 2t -> head (2t)>>6
    float d = 1.f / fmaxf(denom[n * 8 + h], 1e-16f);
    float ax = 0.f, ay = 0.f;
    for (int i = 0; i < cnt; ++i) {
        int e = eidx[start + i];
        int s = src[e];
        float wgt = exp_e[e * 8 + h] * d;
        unsigned v = feat_v[(size_t)s * 256 + t];
        float lo = __uint_as_float(v << 16);
        float hi = __uint_as_float(v & 0xffff0000u);
        ax = fmaf(wgt, lo, ax);
        ay = fmaf(wgt, hi, ay);
    }
    *(float2*)(out + (size_t)n * HF + 2 * t) = make_float2(ax, ay);
}

// ---------------------------------------------------------------------------
extern "C" void kernel_launch(void* const* d_in, const int* in_sizes, int n_in,
                              void* d_out, int out_size, void* d_ws, size_t ws_size,
                              hipStream_t stream) {
    const float* feat   = (const float*)d_in[0];
    const int*   src    = (const int*)d_in[1];
    const int*   dst    = (const int*)d_in[2];
    const float* W_src  = (const float*)d_in[3];
    const float* b_src  = (const float*)d_in[4];
    const float* W_dst  = (const float*)d_in[5];
    const float* b_dst  = (const float*)d_in[6];
    const float* W_val  = (const float*)d_in[7];
    const float* b_val  = (const float*)d_in[8];
    const float* attn_l = (const float*)d_in[9];
    const float* attn_r = (const float*)d_in[10];
    float* out = (float*)d_out;

    char* ws = (char*)d_ws;
    size_t off = 0;
    auto alloc = [&](size_t bytes) -> void* {
        void* p = ws + off;
        off += (bytes + 255) & ~(size_t)255;
        return p;
    };

    unsigned short* feat_bf = (unsigned short*)alloc((size_t)N_PAD * IN_F * 2);
    unsigned short* Wt      = (unsigned short*)alloc((size_t)IN_F * HF * 2);
    unsigned short* feat_v  = (unsigned short*)alloc((size_t)N_PAD * HF * 2);
    float* w_l    = (float*)alloc(4096 * 4);
    float* w_r    = (float*)alloc(4096 * 4);
    float* c_l    = (float*)alloc(8 * 4);
    float* c_r    = (float*)alloc(8 * 4);
    float* el     = (float*)alloc((size_t)N_NODES * 8 * 4);
    float* er     = (float*)alloc((size_t)N_NODES * 8 * 4);
    float* denom  = (float*)alloc((size_t)N_NODES * 8 * 4);
    float* exp_e  = (float*)alloc((size_t)N_EDGES * 8 * 4);
    int*   deg    = (int*)alloc((size_t)N_NODES * 4);
    int*   offs   = (int*)alloc((size_t)N_NODES * 4);
    int*   cursor = (int*)alloc((size_t)N_NODES * 4);
    int*   eidx   = (int*)alloc((size_t)N_EDGES * 4);
    (void)ws_size; (void)in_sizes; (void)n_in; (void)out_size;

    k0_convert<<<12500, 256, 0, stream>>>(feat, feat_bf);
    k0b_wt<<<256, 256, 0, stream>>>(W_val, Wt);
    k1_fold<<<33, 256, 0, stream>>>(W_src, b_src, W_dst, b_dst, attn_l, attn_r,
                                    w_l, w_r, c_l, c_r);
    k2_el_er<<<(N_NODES + 15) / 16, 256, 0, stream>>>(feat, w_l, w_r, c_l, c_r,
                                                      el, er, denom, deg);
    k3_mfma<<<(N_PAD / 128) * 4, 256, 0, stream>>>(feat_bf, Wt, b_val, feat_v);
    k4_hist<<<(N_EDGES + 255) / 256, 256, 0, stream>>>(dst, deg);
    k5_scan<<<1, 1024, 0, stream>>>(deg, offs, cursor);
    k6_scatter<<<(N_EDGES + 255) / 256, 256, 0, stream>>>(dst, cursor, eidx);
    k7_edge<<<(N_EDGES * 8 + 255) / 256, 256, 0, stream>>>(src, dst, el, er, exp_e, denom);
    k8_agg<<<N_NODES, 256, 0, stream>>>(src, eidx, offs, deg, exp_e, denom,
                                        (const unsigned int*)feat_v, out);
}